// Round 1
// baseline (21.945 us; speedup 1.0000x reference)
//
#include <hip/hip_runtime.h>
#include <math.h>

// Problem constants (match reference)
constexpr int B = 32;
constexpr int N = 1024;
constexpr int S = 16;                 // slices per batch
constexpr int ROWS_PER_SLICE = N / S; // 64
constexpr int NBLK = B * S;           // 512 blocks
constexpr int NTHR = 256;

// Main kernel: one block per (batch, slice).
// Threads 0..127  : "rows" side  -> dis1[i] = min_j ||pred_i - gt_j||  (+ l2 term)
// Threads 128..255: "cols" side  -> dis2[j] = min_i ||pred_i - gt_j||
// Each thread owns 2 rows/cols and a quarter (256) of the opposite set.
__global__ __launch_bounds__(NTHR) void chamfer_main(
    const float* __restrict__ dR,   // [B,3,3] delta_rot_pred
    const float* __restrict__ dt,   // [B,3]   delta_trans_pred
    const float* __restrict__ tc,   // [B,3]   trans_cur
    const float* __restrict__ Rc,   // [B,3,3] rot_cur
    const float* __restrict__ G,    // [B,3,3] rot_gt
    const float* __restrict__ g,    // [B,3]   trans_gt
    const float* __restrict__ pts,  // [B,N,3] points_tmp
    const float* __restrict__ sym,  // [B]     sym_flag
    float* __restrict__ partial)    // [NBLK]  per-block partial sums
{
    __shared__ float4 sp[N];          // posed_refined (pred) points
    __shared__ float4 sg[N];          // posed_gt points
    __shared__ float redmin[512];     // [side(2)][row(64)][quarter(4)]
    __shared__ float redsum[NTHR];

    const int blk   = blockIdx.x;
    const int b     = blk / S;
    const int slice = blk % S;
    const int t     = threadIdx.x;

    // ---- uniform per-block transform setup (scalar-register math) ----
    const float* dRb = dR + b * 9;
    const float* Rcb = Rc + b * 9;
    const float* Gb  = G  + b * 9;
    const float* dtb = dt + b * 3;
    const float* tcb = tc + b * 3;
    const float* gb  = g  + b * 3;

    // M = Rc * dR  (posed_refined = M*p + v), v = Rc*dt + tc
    float M[9], v[3], GG[9], gv[3];
    #pragma unroll
    for (int j = 0; j < 3; ++j) {
        #pragma unroll
        for (int i = 0; i < 3; ++i) {
            M[j*3+i] = Rcb[j*3+0] * dRb[0*3+i]
                     + Rcb[j*3+1] * dRb[1*3+i]
                     + Rcb[j*3+2] * dRb[2*3+i];
        }
        v[j] = Rcb[j*3+0] * dtb[0] + Rcb[j*3+1] * dtb[1] + Rcb[j*3+2] * dtb[2] + tcb[j];
        #pragma unroll
        for (int i = 0; i < 3; ++i) GG[j*3+i] = Gb[j*3+i];
        gv[j] = gb[j];
    }

    // ---- stage transformed points into LDS ----
    #pragma unroll
    for (int i = t; i < N; i += NTHR) {
        const float* p = pts + ((size_t)b * N + i) * 3;
        const float px = p[0], py = p[1], pz = p[2];
        const float ax = M[0]*px + M[1]*py + M[2]*pz + v[0];
        const float ay = M[3]*px + M[4]*py + M[5]*pz + v[1];
        const float az = M[6]*px + M[7]*py + M[8]*pz + v[2];
        sp[i] = make_float4(ax, ay, az, 0.f);
        const float cx = GG[0]*px + GG[1]*py + GG[2]*pz + gv[0];
        const float cy = GG[3]*px + GG[4]*py + GG[5]*pz + gv[1];
        const float cz = GG[6]*px + GG[7]*py + GG[8]*pz + gv[2];
        sg[i] = make_float4(cx, cy, cz, 0.f);
    }
    __syncthreads();

    // ---- pairwise-min pass ----
    const int side = t >> 7;        // 0: pred rows vs gt; 1: gt cols vs pred
    const int ti   = t & 127;
    const int rp   = ti & 31;       // row-pair index within slice
    const int q    = ti >> 5;       // quarter of opposite set
    const int r0   = slice * ROWS_PER_SLICE + rp * 2;

    const float4* own = side ? sg : sp;
    const float4* opp = side ? sp : sg;
    const float4 o0 = own[r0];
    const float4 o1 = own[r0 + 1];

    float m0 = 3.4e38f, m1 = 3.4e38f;
    const float4* oppk = opp + q * 256;
    #pragma unroll 8
    for (int k = 0; k < 256; ++k) {
        const float4 qq = oppk[k];
        const float dx0 = o0.x - qq.x, dy0 = o0.y - qq.y, dz0 = o0.z - qq.z;
        m0 = fminf(m0, dx0*dx0 + dy0*dy0 + dz0*dz0);
        const float dx1 = o1.x - qq.x, dy1 = o1.y - qq.y, dz1 = o1.z - qq.z;
        m1 = fminf(m1, dx1*dx1 + dy1*dy1 + dz1*dz1);
    }

    const int rl0 = rp * 2;         // local row in [0,64)
    redmin[side*256 + (rl0    )*4 + q] = m0;
    redmin[side*256 + (rl0 + 1)*4 + q] = m1;
    __syncthreads();

    // ---- combine quarters, compute per-point contribution ----
    const float symb = sym[b];
    float contrib = 0.f;
    if (ti < 64) {  // threads 0..63 (side 0) and 128..191 (side 1)
        const int r = ti;           // local row/col in [0,64)
        const int base = side*256 + r*4;
        const float mm = fminf(fminf(redmin[base+0], redmin[base+1]),
                               fminf(redmin[base+2], redmin[base+3]));
        const float dis = sqrtf(mm);
        if (side == 0) {
            const int gr = slice * ROWS_PER_SLICE + r;
            const float4 a = sp[gr], c = sg[gr];
            const float dx = a.x - c.x, dy = a.y - c.y, dz = a.z - c.z;
            const float l2 = sqrtf(dx*dx + dy*dy + dz*dz);
            contrib = (1.f - symb) * l2 + 0.5f * symb * dis;   // l2 + dis1 half
        } else {
            contrib = 0.5f * symb * dis;                        // dis2 half
        }
    }

    // ---- block sum ----
    redsum[t] = contrib;
    __syncthreads();
    #pragma unroll
    for (int s2 = NTHR / 2; s2 > 0; s2 >>= 1) {
        if (t < s2) redsum[t] += redsum[t + s2];
        __syncthreads();
    }
    if (t == 0) partial[blk] = redsum[0];
}

// Final reduction: 512 partials -> scalar mean
__global__ __launch_bounds__(NBLK) void chamfer_final(
    const float* __restrict__ partial, float* __restrict__ out)
{
    __shared__ float red[NBLK];
    const int t = threadIdx.x;
    red[t] = partial[t];
    __syncthreads();
    #pragma unroll
    for (int s2 = NBLK / 2; s2 > 0; s2 >>= 1) {
        if (t < s2) red[t] += red[t + s2];
        __syncthreads();
    }
    if (t == 0) out[0] = red[0] * (1.0f / (float)(B * N));
}

extern "C" void kernel_launch(void* const* d_in, const int* in_sizes, int n_in,
                              void* d_out, int out_size, void* d_ws, size_t ws_size,
                              hipStream_t stream) {
    const float* dR  = (const float*)d_in[0];  // delta_rot_pred [B,3,3]
    const float* dt  = (const float*)d_in[1];  // delta_trans_pred [B,3]
    const float* tc  = (const float*)d_in[2];  // trans_cur [B,3]
    const float* Rc  = (const float*)d_in[3];  // rot_cur [B,3,3]
    const float* G   = (const float*)d_in[4];  // rot_gt [B,3,3]
    const float* g   = (const float*)d_in[5];  // trans_gt [B,3]
    const float* pts = (const float*)d_in[6];  // points_tmp [B,N,3]
    const float* sym = (const float*)d_in[7];  // sym_flag [B]

    float* partial = (float*)d_ws;             // NBLK floats of scratch
    float* out     = (float*)d_out;

    chamfer_main<<<NBLK, NTHR, 0, stream>>>(dR, dt, tc, Rc, G, g, pts, sym, partial);
    chamfer_final<<<1, NBLK, 0, stream>>>(partial, out);
}

// Round 2
// 17.492 us; speedup vs baseline: 1.2546x; 1.2546x over previous
//
#include <hip/hip_runtime.h>
#include <math.h>

// Problem constants (match reference)
constexpr int B = 32;
constexpr int N = 1024;
constexpr int S = 32;                 // slices per batch
constexpr int R = N / S;              // 32 rows per slice
constexpr int NBLK = B * S;           // 1024 blocks
constexpr int NTHR = 256;
constexpr int RPT = 8;                // rows per thread
constexpr int CHUNKS = 32;            // column chunks per side
constexpr int CPC = N / CHUNKS;       // 32 cols per chunk

// One block per (batch, slice).
// side 0 (t<128): pred rows of this slice vs ALL gt cols   -> dis1 rows
// side 1 (t>=128): gt rows of this slice vs ALL pred cols  -> dis2 rows
// Within a side: group = ti>>5 owns 8 rows; chunk = ti&31 owns 32 cols.
// Chunk-min reduced across the 32 lanes of each half-wave via shfl_xor.
__global__ __launch_bounds__(NTHR, 4) void chamfer_main(
    const float* __restrict__ dR,   // [B,3,3] delta_rot_pred
    const float* __restrict__ dt,   // [B,3]   delta_trans_pred
    const float* __restrict__ tc,   // [B,3]   trans_cur
    const float* __restrict__ Rc,   // [B,3,3] rot_cur
    const float* __restrict__ G,    // [B,3,3] rot_gt
    const float* __restrict__ g,    // [B,3]   trans_gt
    const float* __restrict__ pts,  // [B,N,3] points_tmp
    const float* __restrict__ sym,  // [B]     sym_flag
    float* __restrict__ partial)    // [NBLK]  per-block partial sums
{
    __shared__ float4 sp[N];          // posed_refined (pred): xyz + |a|^2
    __shared__ float4 sg[N];          // posed_gt:             xyz + |c|^2
    __shared__ float wsum[NTHR / 64];

    const int blk   = blockIdx.x;
    const int b     = blk / S;
    const int slice = blk % S;
    const int t     = threadIdx.x;

    // ---- uniform per-block transform setup ----
    const float* dRb = dR + b * 9;
    const float* Rcb = Rc + b * 9;
    const float* Gb  = G  + b * 9;
    const float* dtb = dt + b * 3;
    const float* tcb = tc + b * 3;
    const float* gb  = g  + b * 3;
    const float symb = sym[b];

    // M = Rc * dR  (posed_refined = M*p + v), v = Rc*dt + tc
    float M[9], v[3];
    #pragma unroll
    for (int j = 0; j < 3; ++j) {
        #pragma unroll
        for (int i = 0; i < 3; ++i) {
            M[j*3+i] = Rcb[j*3+0] * dRb[0*3+i]
                     + Rcb[j*3+1] * dRb[1*3+i]
                     + Rcb[j*3+2] * dRb[2*3+i];
        }
        v[j] = Rcb[j*3+0] * dtb[0] + Rcb[j*3+1] * dtb[1] + Rcb[j*3+2] * dtb[2] + tcb[j];
    }

    float acc = 0.f;   // this thread's contribution to the block partial

    // ---- stage transformed points into LDS (+ fused l2 term) ----
    #pragma unroll
    for (int i = t; i < N; i += NTHR) {
        const float* p = pts + ((size_t)b * N + i) * 3;
        const float px = p[0], py = p[1], pz = p[2];
        const float ax = M[0]*px + M[1]*py + M[2]*pz + v[0];
        const float ay = M[3]*px + M[4]*py + M[5]*pz + v[1];
        const float az = M[6]*px + M[7]*py + M[8]*pz + v[2];
        const float cx = Gb[0]*px + Gb[1]*py + Gb[2]*pz + gb[0];
        const float cy = Gb[3]*px + Gb[4]*py + Gb[5]*pz + gb[1];
        const float cz = Gb[6]*px + Gb[7]*py + Gb[8]*pz + gb[2];
        sp[i] = make_float4(ax, ay, az, ax*ax + ay*ay + az*az);
        sg[i] = make_float4(cx, cy, cz, cx*cx + cy*cy + cz*cz);
        if (slice == 0) {   // l2 term counted exactly once per batch
            const float dx = ax - cx, dy = ay - cy, dz = az - cz;
            acc += (1.f - symb) * sqrtf(dx*dx + dy*dy + dz*dz);
        }
    }
    __syncthreads();

    // ---- per-thread row fragments ----
    const int side  = t >> 7;       // 0: pred rows; 1: gt rows
    const int ti    = t & 127;
    const int chunk = ti & (CHUNKS - 1);
    const int group = ti >> 5;      // 0..3
    const int r0    = slice * R + group * RPT;

    const float4* own = side ? sg : sp;
    const float4* opp = side ? sp : sg;

    float nx[RPT], ny[RPT], nz[RPT], p2[RPT];
    #pragma unroll
    for (int r = 0; r < RPT; ++r) {
        const float4 o = own[r0 + r];
        nx[r] = -2.f * o.x;
        ny[r] = -2.f * o.y;
        nz[r] = -2.f * o.z;
        p2[r] = o.w;
    }

    // ---- pairwise-min main loop: f = |q|^2 - 2 p.q  (3 fma + 1 min / pair) ----
    const float4* qp = opp + chunk * CPC;
    float mins[RPT];
    #pragma unroll
    for (int r = 0; r < RPT; ++r) mins[r] = 3.4e38f;

    #pragma unroll 8
    for (int k = 0; k < CPC; ++k) {
        const int kk = (k + chunk) & (CPC - 1);   // stagger: avoid bank pileup
        const float4 q = qp[kk];
        #pragma unroll
        for (int r = 0; r < RPT; ++r) {
            const float f = fmaf(nx[r], q.x, fmaf(ny[r], q.y, fmaf(nz[r], q.z, q.w)));
            mins[r] = fminf(mins[r], f);
        }
    }

    // ---- reduce chunk-mins across the 32 lanes of this group ----
    #pragma unroll
    for (int r = 0; r < RPT; ++r) {
        #pragma unroll
        for (int m = 1; m <= 16; m <<= 1)
            mins[r] = fminf(mins[r], __shfl_xor(mins[r], m));
    }
    if ((ti & 31) == 0) {
        #pragma unroll
        for (int r = 0; r < RPT; ++r) {
            const float d2 = fmaxf(mins[r] + p2[r], 0.f);
            acc += 0.5f * symb * sqrtf(d2);
        }
    }

    // ---- block sum: full-wave shfl reduce, then tiny LDS combine ----
    #pragma unroll
    for (int m = 1; m <= 32; m <<= 1) acc += __shfl_xor(acc, m);
    if ((t & 63) == 0) wsum[t >> 6] = acc;
    __syncthreads();
    if (t == 0) partial[blk] = (wsum[0] + wsum[1]) + (wsum[2] + wsum[3]);
}

// Final reduction: 1024 partials -> scalar mean
__global__ __launch_bounds__(256) void chamfer_final(
    const float* __restrict__ partial, float* __restrict__ out)
{
    __shared__ float wsum[4];
    const int t = threadIdx.x;
    const float4 v = ((const float4*)partial)[t];   // 256 * 4 = 1024
    float a = (v.x + v.y) + (v.z + v.w);
    #pragma unroll
    for (int m = 1; m <= 32; m <<= 1) a += __shfl_xor(a, m);
    if ((t & 63) == 0) wsum[t >> 6] = a;
    __syncthreads();
    if (t == 0) out[0] = ((wsum[0] + wsum[1]) + (wsum[2] + wsum[3])) * (1.0f / (float)(B * N));
}

extern "C" void kernel_launch(void* const* d_in, const int* in_sizes, int n_in,
                              void* d_out, int out_size, void* d_ws, size_t ws_size,
                              hipStream_t stream) {
    const float* dR  = (const float*)d_in[0];  // delta_rot_pred [B,3,3]
    const float* dt  = (const float*)d_in[1];  // delta_trans_pred [B,3]
    const float* tc  = (const float*)d_in[2];  // trans_cur [B,3]
    const float* Rc  = (const float*)d_in[3];  // rot_cur [B,3,3]
    const float* G   = (const float*)d_in[4];  // rot_gt [B,3,3]
    const float* g   = (const float*)d_in[5];  // trans_gt [B,3]
    const float* pts = (const float*)d_in[6];  // points_tmp [B,N,3]
    const float* sym = (const float*)d_in[7];  // sym_flag [B]

    float* partial = (float*)d_ws;             // NBLK floats of scratch
    float* out     = (float*)d_out;

    chamfer_main<<<NBLK, NTHR, 0, stream>>>(dR, dt, tc, Rc, G, g, pts, sym, partial);
    chamfer_final<<<1, 256, 0, stream>>>(partial, out);
}